// Round 3
// baseline (966.741 us; speedup 1.0000x reference)
//
#include <hip/hip_runtime.h>

#define D_MODEL 256
#define DK      64
#define KN      32      // neighbors per query
#define TN      16      // n-rows per block
#define NB      10000
#define BB      2

// ---------------------------------------------------------------------------
// Kernel 1: Mt[d'][d] = sum_e w_qs[e][d'] * w_ks[e][d]   (256x256, tiny)
// Folds both no-bias Linear layers: scores = (q @ Mt) . k_row
// ---------------------------------------------------------------------------
__global__ void compute_mt(const float* __restrict__ wqs,
                           const float* __restrict__ wks,
                           float* __restrict__ mt) {
    const int dp = blockIdx.x;   // 0..255 (uniform per block -> s_loads on wqs)
    const int d  = threadIdx.x;  // 0..255 (coalesced on wks)
    float acc = 0.f;
#pragma unroll
    for (int e = 0; e < DK; ++e)
        acc = fmaf(wqs[e * D_MODEL + dp], wks[e * D_MODEL + d], acc);
    mt[dp * D_MODEL + d] = acc;
}

// ---------------------------------------------------------------------------
// Kernel 2: fused  qt = q@Mt,  scores = qt.k,  softmax,  out = attn.v,  q2 = q
// Grid: BB * (NB/TN) blocks of 256 threads. Block owns TN=16 consecutive rows.
// ---------------------------------------------------------------------------
__global__ __launch_bounds__(256, 4) void attn_main(
        const float* __restrict__ q, const float* __restrict__ k,
        const float* __restrict__ v, const float* __restrict__ mt,
        float* __restrict__ out, float* __restrict__ q2)
{
    __shared__ float q_lds[TN][D_MODEL];   // 16 KB
    __shared__ float qt_lds[TN][D_MODEL];  // 16 KB

    const int blk = blockIdx.x;                 // 0..1249
    const int bi  = blk / (NB / TN);            // batch 0..1
    const int n0  = (blk % (NB / TN)) * TN;     // first local row
    const int t   = threadIdx.x;
    const long long rowbase = (long long)bi * NB + n0;  // global row of r=0

    // ---- stage q tile into LDS, emit q2 copy (q2 == q) -------------------
#pragma unroll
    for (int j = 0; j < (TN * D_MODEL / 4) / 256; ++j) {   // 4 iters
        const int cid = j * 256 + t;           // float4 id within tile
        const int r   = cid >> 6;              // row   (64 float4 per row)
        const int c4  = cid & 63;              // col/4
        const float4 val =
            *(const float4*)&q[(rowbase + r) * D_MODEL + c4 * 4];
        *(float4*)&q_lds[r][c4 * 4] = val;
        *(float4*)&q2[(rowbase + r) * D_MODEL + c4 * 4] = val;
    }
    __syncthreads();

    // ---- qt[r][d] = sum_c q[r][c] * Mt[c][d];  thread owns column d = t --
    float acc[TN];
#pragma unroll
    for (int r = 0; r < TN; ++r) acc[r] = 0.f;
    for (int c = 0; c < D_MODEL; c += 4) {
        // coalesced L2-resident reads (256B per wave per load)
        const float m0 = mt[(c + 0) * D_MODEL + t];
        const float m1 = mt[(c + 1) * D_MODEL + t];
        const float m2 = mt[(c + 2) * D_MODEL + t];
        const float m3 = mt[(c + 3) * D_MODEL + t];
#pragma unroll
        for (int r = 0; r < TN; ++r) {
            const float4 q4 = *(const float4*)&q_lds[r][c];  // LDS broadcast
            acc[r] = fmaf(q4.x, m0, acc[r]);
            acc[r] = fmaf(q4.y, m1, acc[r]);
            acc[r] = fmaf(q4.z, m2, acc[r]);
            acc[r] = fmaf(q4.w, m3, acc[r]);
        }
    }
#pragma unroll
    for (int r = 0; r < TN; ++r) qt_lds[r][t] = acc[r];
    __syncthreads();

    // ---- attention: wave w owns rows w*4 .. w*4+3 ------------------------
    const int wave = t >> 6;
    const int lane = t & 63;
    for (int rr = 0; rr < 4; ++rr) {
        const int r = wave * 4 + rr;
        const long long n = rowbase + r;

        // each lane holds qt[r][lane*4 .. lane*4+3]
        const float4 qt4 = *(const float4*)&qt_lds[r][lane * 4];

        // scores: 32 neighbors, 256-dot each; 1KB coalesced load per neighbor
        const float* krow = k + n * (long long)(KN * D_MODEL);
        float p[KN];
#pragma unroll
        for (int kk = 0; kk < KN; ++kk) {
            const float4 k4 =
                *(const float4*)&krow[kk * D_MODEL + lane * 4];
            p[kk] = qt4.x * k4.x + qt4.y * k4.y + qt4.z * k4.z + qt4.w * k4.w;
        }
        // full 64-lane butterfly reduce for each neighbor
#pragma unroll
        for (int kk = 0; kk < KN; ++kk) {
#pragma unroll
            for (int s = 1; s < 64; s <<= 1)
                p[kk] += __shfl_xor(p[kk], s);
        }

        // softmax over the 32 scores (every lane has all of them)
        float mx = p[0];
#pragma unroll
        for (int kk = 1; kk < KN; ++kk) mx = fmaxf(mx, p[kk]);
        float ssum = 0.f;
#pragma unroll
        for (int kk = 0; kk < KN; ++kk) {
            p[kk] = __expf(p[kk] - mx);
            ssum += p[kk];
        }
        const float inv = 1.f / ssum;

        // out[n][lane] = sum_kk attn[kk] * v[n][kk][lane]   (lane = d, 0..63)
        const float* vrow = v + n * (long long)(KN * DK);
        float o = 0.f;
#pragma unroll
        for (int kk = 0; kk < KN; ++kk)
            o = fmaf(p[kk] * inv, vrow[kk * DK + lane], o);
        out[n * DK + lane] = o;
    }
}

extern "C" void kernel_launch(void* const* d_in, const int* in_sizes, int n_in,
                              void* d_out, int out_size, void* d_ws, size_t ws_size,
                              hipStream_t stream) {
    const float* q   = (const float*)d_in[0];  // [B,N,256]
    const float* k   = (const float*)d_in[1];  // [B,N,32,256]
    const float* v   = (const float*)d_in[2];  // [B,N,32,64]
    const float* wqs = (const float*)d_in[3];  // [64,256]
    const float* wks = (const float*)d_in[4];  // [64,256]

    float* out = (float*)d_out;                     // [B,N,64]   (first output)
    float* q2  = out + (size_t)BB * NB * DK;        // [B,N,256]  (second output)
    float* mt  = (float*)d_ws;                      // 256KB scratch

    compute_mt<<<D_MODEL, D_MODEL, 0, stream>>>(wqs, wks, mt);
    attn_main<<<BB * (NB / TN), 256, 0, stream>>>(q, k, v, mt, out, q2);
}